// Round 4
// baseline (538.056 us; speedup 1.0000x reference)
//
#include <hip/hip_runtime.h>
#include <hip/hip_bf16.h>
#include <cstdint>

#define N_NODES 51200
#define N_GRAPH 256
#define NPG     200
#define N_EDGE  409600
#define EPG     1600
#define F_IN    768
#define HID     128
#define HEADS   4
#define HC      512   // HEADS*HID

typedef __attribute__((ext_vector_type(8))) short short8;
typedef __attribute__((ext_vector_type(4))) float floatx4;

// ---------------- workspace layout (bytes) ----------------
constexpr size_t OFF_H1B    = 0;                                       // bf16 [N,512]
constexpr size_t OFF_H2B    = OFF_H1B + (size_t)N_NODES * HC * 2;      // bf16 [N,128]
constexpr size_t OFF_H2F    = OFF_H2B + (size_t)N_NODES * HID * 2;     // (unused)
constexpr size_t OFF_WT1    = OFF_H2F + (size_t)N_NODES * HID * 4;     // bf16 [512][768]
constexpr size_t OFF_WT2    = OFF_WT1 + (size_t)HC * F_IN * 2;         // bf16 [128][512]
constexpr size_t OFF_S      = OFF_WT2 + (size_t)HID * HC * 2;          // (unused)
constexpr size_t OFF_AGG    = OFF_S + (size_t)N_NODES * 2 * 4;
constexpr size_t OFF_SUB    = OFF_AGG + (size_t)N_GRAPH * 4 * 4;
constexpr size_t OFF_EORD   = OFF_SUB + (size_t)N_GRAPH * HID * 4;     // u16 [G][EPG] CSR-ordered pk
constexpr size_t OFF_ROWS   = OFF_EORD + (size_t)N_GRAPH * EPG * 2;    // i32 [G][NPG+1]

__device__ __forceinline__ float leaky(float x) { return x >= 0.0f ? x : 0.2f * x; }

__device__ __forceinline__ unsigned short f2bf(float f) {
    unsigned int u = __float_as_uint(f);
    u += 0x7fffu + ((u >> 16) & 1u);            // RNE
    return (unsigned short)(u >> 16);
}
__device__ __forceinline__ float bflo(int p) { return __uint_as_float((unsigned)p << 16); }
__device__ __forceinline__ float bfhi(int p) { return __uint_as_float((unsigned)p & 0xffff0000u); }

__device__ __forceinline__ unsigned int cvtpk(float lo, float hi) {
    unsigned int r;
    asm("v_cvt_pk_bf16_f32 %0, %1, %2" : "=v"(r) : "v"(lo), "v"(hi));
    return r;
}

__device__ __forceinline__ void gl_lds16(const void* g, void* l) {
    __builtin_amdgcn_global_load_lds(
        (__attribute__((address_space(1))) void*)(g),
        (__attribute__((address_space(3))) void*)(l),
        16, 0, 0);
}

// ---------------- W [K][N] fp32 -> Wt [N][K] bf16 ----------------
__global__ __launch_bounds__(256)
void transpose_cvt_kernel(const float* __restrict__ W, short* __restrict__ Wt,
                          int K, int Nn)
{
    int idx = blockIdx.x * 256 + threadIdx.x;
    if (idx >= K * Nn) return;
    int k = idx / Nn, n = idx % Nn;
    Wt[(size_t)n * K + k] = (short)f2bf(W[idx]);
}

// ---------------- GEMM1: 64x128 tile, fp32 A staged raw, cvt on LDS read -------------
// v5: occupancy-first. acc = 2x4 frags (32 regs) -> ~100 regs total -> 4 blocks/CU.
// 2-buffer, stage-first, full-drain barrier; TLP (16 waves/CU) hides latency.
__global__ __launch_bounds__(256, 4)
void gemm_xw1_kernel(const float* __restrict__ A, const short* __restrict__ Bt,
                     unsigned short* __restrict__ C, int M, int Nn, int K)
{
    __shared__ __align__(16) float Asm[2][64 * 32];    // 16 KB
    __shared__ __align__(16) short Bsm[2][4096];       // 16 KB
    const int tid = threadIdx.x;
    const int w = tid >> 6, l = tid & 63;

    const int nwg = gridDim.x;                          // %8==0
    int wg = blockIdx.x;
    wg = (wg & 7) * (nwg >> 3) + (wg >> 3);
    const int nbx = Nn >> 7;
    const int m0 = (wg / nbx) * 64;
    const int n0 = (wg % nbx) * 128;
    const int wr = w >> 1, wc = w & 1;

    floatx4 acc[2][4];
#pragma unroll
    for (int i = 0; i < 2; ++i)
#pragma unroll
        for (int j = 0; j < 4; ++j) acc[i][j] = (floatx4)0.0f;

    const short* bgp = Bt + (size_t)(n0 + w * 32 + (l & 15)) * K + ((l >> 4) * 8);
    const float* agp = A + (size_t)(m0 + w * 16 + (l & 7)) * K + ((l >> 3) * 4);
    const int nt = K >> 5;      // 24

    // A frag float-offsets: chunk layout 8 rows x 32 floats, lane wrote at l*4
    int aB[2];
#pragma unroll
    for (int mi = 0; mi < 2; ++mi) {
        const int r = wr * 32 + mi * 16 + (l & 15);
        aB[mi] = (r >> 3) * 256 + ((l >> 4) * 8 >> 2) * 32 + (r & 7) * 4;
    }
    const int bB0 = wc * 2048 + l * 8;                 // shorts

#define STAGE1(buf, t) {                                                        \
        const int ko_ = (t) * 32;                                               \
        gl_lds16(agp + ko_,              &Asm[buf][w * 512]);                   \
        gl_lds16(agp + 8 * K + ko_,      &Asm[buf][w * 512 + 256]);             \
        gl_lds16(bgp + ko_,              &Bsm[buf][w * 1024]);                  \
        gl_lds16(bgp + 16 * K + ko_,     &Bsm[buf][w * 1024 + 512]); }

#define COMPUTE1(buf) {                                                         \
        short8 af[2], bfr[4];                                                   \
        _Pragma("unroll")                                                       \
        for (int mi = 0; mi < 2; ++mi) {                                        \
            float4 v0 = *(const float4*)&Asm[buf][aB[mi]];                      \
            float4 v1 = *(const float4*)&Asm[buf][aB[mi] + 32];                 \
            uint4 pk;                                                           \
            pk.x = cvtpk(v0.x, v0.y); pk.y = cvtpk(v0.z, v0.w);                 \
            pk.z = cvtpk(v1.x, v1.y); pk.w = cvtpk(v1.z, v1.w);                 \
            af[mi] = *reinterpret_cast<short8*>(&pk);                           \
        }                                                                       \
        _Pragma("unroll")                                                       \
        for (int ni = 0; ni < 4; ++ni)                                          \
            bfr[ni] = *(const short8*)&Bsm[buf][bB0 + ni * 512];                \
        _Pragma("unroll")                                                       \
        for (int mi = 0; mi < 2; ++mi)                                          \
            _Pragma("unroll")                                                   \
            for (int ni = 0; ni < 4; ++ni)                                      \
                acc[mi][ni] = __builtin_amdgcn_mfma_f32_16x16x32_bf16(          \
                    af[mi], bfr[ni], acc[mi][ni], 0, 0, 0); }

    STAGE1(0, 0);
    __syncthreads();

    int cur = 0;
    for (int t = 0; t < nt; ++t) {
        if (t + 1 < nt) STAGE1(cur ^ 1, t + 1);
        COMPUTE1(cur);
        __syncthreads();                 // drains vmcnt for next buf; 4 blocks/CU hide it
        cur ^= 1;
    }
#undef STAGE1
#undef COMPUTE1

    const int lr = (l >> 4) * 4, lc = l & 15;
#pragma unroll
    for (int mi = 0; mi < 2; ++mi)
#pragma unroll
        for (int ni = 0; ni < 4; ++ni) {
            const size_t base = (size_t)(m0 + wr * 32 + mi * 16 + lr) * Nn
                              + (n0 + wc * 64 + ni * 16 + lc);
#pragma unroll
            for (int rr = 0; rr < 4; ++rr)
                C[base + (size_t)rr * Nn] = f2bf(acc[mi][ni][rr]);
        }
}

// ---------------- GEMM2: 64x128 tile, bf16 A ----------------
__global__ __launch_bounds__(256, 4)
void gemm_bf16_kernel(const short* __restrict__ Ab, const short* __restrict__ Bt,
                      unsigned short* __restrict__ C, int M, int Nn, int K)
{
    __shared__ __align__(16) short Asm[2][2048];       // 8 KB
    __shared__ __align__(16) short Bsm[2][4096];       // 16 KB
    const int tid = threadIdx.x;
    const int w = tid >> 6, l = tid & 63;

    const int nwg = gridDim.x;
    int wg = blockIdx.x;
    wg = (wg & 7) * (nwg >> 3) + (wg >> 3);
    const int nbx = Nn >> 7;
    const int m0 = (wg / nbx) * 64;
    const int n0 = (wg % nbx) * 128;
    const int wr = w >> 1, wc = w & 1;

    floatx4 acc[2][4];
#pragma unroll
    for (int i = 0; i < 2; ++i)
#pragma unroll
        for (int j = 0; j < 4; ++j) acc[i][j] = (floatx4)0.0f;

    const short* bgp = Bt + (size_t)(n0 + w * 32 + (l & 15)) * K + ((l >> 4) * 8);
    const short* agp = Ab + (size_t)(m0 + w * 16 + (l & 15)) * K + ((l >> 4) * 8);
    const int nt = K >> 5;

    const int bB0 = wc * 2048 + l * 8;

#define STAGE2(buf, t) {                                                        \
        const int ko_ = (t) * 32;                                               \
        gl_lds16(agp + ko_,              &Asm[buf][w * 512]);                   \
        gl_lds16(bgp + ko_,              &Bsm[buf][w * 1024]);                  \
        gl_lds16(bgp + 16 * K + ko_,     &Bsm[buf][w * 1024 + 512]); }

#define COMPUTE2(buf) {                                                         \
        short8 af[2], bfr[4];                                                   \
        _Pragma("unroll")                                                       \
        for (int mi = 0; mi < 2; ++mi)                                          \
            af[mi] = *(const short8*)&Asm[buf][(wr * 2 + mi) * 512 + l * 8];    \
        _Pragma("unroll")                                                       \
        for (int ni = 0; ni < 4; ++ni)                                          \
            bfr[ni] = *(const short8*)&Bsm[buf][bB0 + ni * 512];                \
        _Pragma("unroll")                                                       \
        for (int mi = 0; mi < 2; ++mi)                                          \
            _Pragma("unroll")                                                   \
            for (int ni = 0; ni < 4; ++ni)                                      \
                acc[mi][ni] = __builtin_amdgcn_mfma_f32_16x16x32_bf16(          \
                    af[mi], bfr[ni], acc[mi][ni], 0, 0, 0); }

    STAGE2(0, 0);
    __syncthreads();

    int cur = 0;
    for (int t = 0; t < nt; ++t) {
        if (t + 1 < nt) STAGE2(cur ^ 1, t + 1);
        COMPUTE2(cur);
        __syncthreads();
        cur ^= 1;
    }
#undef STAGE2
#undef COMPUTE2

    const int lr = (l >> 4) * 4, lc = l & 15;
#pragma unroll
    for (int mi = 0; mi < 2; ++mi)
#pragma unroll
        for (int ni = 0; ni < 4; ++ni) {
            const size_t base = (size_t)(m0 + wr * 32 + mi * 16 + lr) * Nn
                              + (n0 + wc * 64 + ni * 16 + lc);
#pragma unroll
            for (int rr = 0; rr < 4; ++rr)
                C[base + (size_t)rr * Nn] = f2bf(acc[mi][ni][rr]);
        }
}

// ---------------- CSR prep: one block per graph, built ONCE for gat1(x4)+gat2 --------
__global__ __launch_bounds__(256)
void csr_kernel(const int* __restrict__ src0, const int* __restrict__ dst0,
                unsigned short* __restrict__ eord, int* __restrict__ rows)
{
    const int g = blockIdx.x, tid = threadIdx.x;
    __shared__ unsigned short s_eraw[EPG];
    __shared__ int s_cnt[NPG];
    __shared__ int s_scan[256];
    __shared__ int s_row[NPG + 1];
    const int gbase = g * NPG;

    if (tid < NPG) s_cnt[tid] = 0;
    for (int j = tid; j < EPG; j += 256) {
        int s = src0[g * EPG + j] - gbase;
        int d = dst0[g * EPG + j] - gbase;
        s_eraw[j] = (unsigned short)(s | (d << 8));
    }
    __syncthreads();
    for (int j = tid; j < EPG; j += 256)
        atomicAdd(&s_cnt[s_eraw[j] >> 8], 1);
    __syncthreads();
    {
        int v = (tid < NPG) ? s_cnt[tid] : 0;
        s_scan[tid] = v;
        __syncthreads();
        for (int off = 1; off < 256; off <<= 1) {
            int u = (tid >= off) ? s_scan[tid - off] : 0;
            __syncthreads();
            s_scan[tid] += u;
            __syncthreads();
        }
        if (tid < NPG) s_row[tid + 1] = s_scan[tid];
        if (tid == 0) s_row[0] = 0;
        __syncthreads();
        if (tid < NPG) s_scan[tid] = s_row[tid];   // cursors
    }
    __syncthreads();
    for (int j = tid; j < EPG; j += 256) {
        int pk = s_eraw[j];
        int p = atomicAdd(&s_scan[pk >> 8], 1);
        eord[(size_t)g * EPG + p] = (unsigned short)pk;
    }
    if (tid <= NPG) rows[g * (NPG + 1) + tid] = s_row[tid];
}

// ---------------- GAT layer 1: prebuilt CSR, 8 waves ----------------
__global__ __launch_bounds__(512)
void gat1_kernel(const unsigned short* __restrict__ H,
                 const unsigned short* __restrict__ eord, const int* __restrict__ rows,
                 const float* __restrict__ a_s, const float* __restrict__ a_d,
                 const float* __restrict__ b1, unsigned short* __restrict__ out)
{
    const int g = blockIdx.x, h = blockIdx.y;
    __shared__ int   s_feat[NPG * 64];            // 51.2 KB
    __shared__ float s_as[NPG], s_ad[NPG], s_m[NPG], s_inv[NPG];
    __shared__ int   s_row[NPG + 1];
    __shared__ int2  s_wc[EPG];                   // 12.8 KB
    const int tid = threadIdx.x, w = tid >> 6, l = tid & 63;
    const int gbase = g * NPG;

    // stage feats + CSR
    for (int flat = tid; flat < NPG * 16; flat += 512) {
        int row = flat >> 4, q = flat & 15;
        uint4 v = *(const uint4*)(H + (size_t)(gbase + row) * HC + h * HID + q * 8);
        *(uint4*)&s_feat[row * 64 + q * 4] = v;
    }
    for (int j = tid; j < EPG; j += 512)
        s_wc[j].y = eord[(size_t)g * EPG + j];
    if (tid <= NPG) s_row[tid] = rows[g * (NPG + 1) + tid];
    __syncthreads();

    // attention dots (wave per node)
    const float2 av = ((const float2*)(a_s + h * HID))[l];
    const float2 dv = ((const float2*)(a_d + h * HID))[l];
    for (int nl = w; nl < NPG; nl += 8) {
        int pk = s_feat[nl * 64 + l];
        float f0 = bflo(pk), f1 = bfhi(pk);
        float ss = f0 * av.x + f1 * av.y;
        float sd = f0 * dv.x + f1 * dv.y;
#pragma unroll
        for (int off = 1; off < 64; off <<= 1) {
            ss += __shfl_xor(ss, off);
            sd += __shfl_xor(sd, off);
        }
        if (l == 0) { s_as[nl] = ss; s_ad[nl] = sd; }
    }
    __syncthreads();

    // logits
    for (int j = tid; j < EPG; j += 512) {
        int pk = s_wc[j].y;
        s_wc[j].x = __float_as_int(leaky(s_as[pk & 255] + s_ad[pk >> 8]));
    }
    __syncthreads();

    // per-node max
    if (tid < NPG) {
        float m = leaky(s_as[tid] + s_ad[tid]);
        int r0 = s_row[tid], r1 = s_row[tid + 1];
        for (int j = r0; j < r1; ++j) m = fmaxf(m, __int_as_float(s_wc[j].x));
        s_m[tid] = m;
    }
    __syncthreads();

    // exp
    for (int j = tid; j < EPG; j += 512) {
        int2 e = s_wc[j];
        s_wc[j].x = __float_as_int(__expf(__int_as_float(e.x) - s_m[e.y >> 8]));
    }
    __syncthreads();

    // per-node sum -> inv
    if (tid < NPG) {
        float rs = __expf(leaky(s_as[tid] + s_ad[tid]) - s_m[tid]);
        int r0 = s_row[tid], r1 = s_row[tid + 1];
        for (int j = r0; j < r1; ++j) rs += __int_as_float(s_wc[j].x);
        s_inv[tid] = 1.0f / (rs + 1e-16f);
    }
    __syncthreads();

    // aggregation
    const float2 bv = ((const float2*)(b1 + h * HID))[l];
    for (int nl = w; nl < NPG; nl += 8) {
        const int r0 = s_row[nl], r1 = s_row[nl + 1];
        const float wself = __expf(leaky(s_as[nl] + s_ad[nl]) - s_m[nl]);
        int spk = s_feat[nl * 64 + l];
        float a0 = wself * bflo(spk), a1 = wself * bfhi(spk);
        float c0 = 0.0f, c1 = 0.0f;
        int j = r0;
        for (; j + 4 <= r1; j += 4) {
            int2 e0 = s_wc[j], e1 = s_wc[j + 1], e2 = s_wc[j + 2], e3 = s_wc[j + 3];
            int p0 = s_feat[(e0.y & 255) * 64 + l];
            int p1 = s_feat[(e1.y & 255) * 64 + l];
            int p2 = s_feat[(e2.y & 255) * 64 + l];
            int p3 = s_feat[(e3.y & 255) * 64 + l];
            float w0 = __int_as_float(e0.x), w1 = __int_as_float(e1.x);
            float w2 = __int_as_float(e2.x), w3 = __int_as_float(e3.x);
            a0 += w0 * bflo(p0); a1 += w0 * bfhi(p0);
            c0 += w1 * bflo(p1); c1 += w1 * bfhi(p1);
            a0 += w2 * bflo(p2); a1 += w2 * bfhi(p2);
            c0 += w3 * bflo(p3); c1 += w3 * bfhi(p3);
        }
        for (; j < r1; ++j) {
            int2 e0 = s_wc[j];
            int p0 = s_feat[(e0.y & 255) * 64 + l];
            float w0 = __int_as_float(e0.x);
            a0 += w0 * bflo(p0); a1 += w0 * bfhi(p0);
        }
        const float inv = s_inv[nl];
        float o0 = (a0 + c0) * inv + bv.x;
        float o1 = (a1 + c1) * inv + bv.y;
        unsigned int st = (unsigned int)f2bf(fmaxf(o0, 0.0f))
                        | ((unsigned int)f2bf(fmaxf(o1, 0.0f)) << 16);
        *(unsigned int*)&out[(size_t)(gbase + nl) * HC + h * HID + 2 * l] = st;
    }
}

// ---------------- GAT layer 2 + cluster softmax + fused sub-pool + S^T A S -----------
__global__ __launch_bounds__(512)
void gat2_kernel(const unsigned short* __restrict__ H,
                 const unsigned short* __restrict__ eord, const int* __restrict__ rows,
                 const float* __restrict__ a_s, const float* __restrict__ a_d,
                 const float* __restrict__ b2, const float* __restrict__ Wc,
                 const float* __restrict__ bc,
                 float* __restrict__ sub, float* __restrict__ agg)
{
    const int g = blockIdx.x;
    __shared__ int   s_feat[NPG * 64];
    __shared__ float s_as[NPG], s_ad[NPG], s_m[NPG], s_inv[NPG];
    __shared__ int   s_row[NPG + 1];
    __shared__ int2  s_wc[EPG];
    __shared__ float2 s_Sv[NPG];
    __shared__ float  s_red[8 * 128];
    __shared__ float  s_aggr[8][4];
    const int tid = threadIdx.x, w = tid >> 6, l = tid & 63;
    const int gbase = g * NPG;

    for (int flat = tid; flat < NPG * 16; flat += 512) {
        int row = flat >> 4, q = flat & 15;
        uint4 v = *(const uint4*)(H + (size_t)(gbase + row) * HID + q * 8);
        *(uint4*)&s_feat[row * 64 + q * 4] = v;
    }
    for (int j = tid; j < EPG; j += 512)
        s_wc[j].y = eord[(size_t)g * EPG + j];
    if (tid <= NPG) s_row[tid] = rows[g * (NPG + 1) + tid];
    __syncthreads();

    const float2 av = ((const float2*)a_s)[l];
    const float2 dv = ((const float2*)a_d)[l];
    for (int nl = w; nl < NPG; nl += 8) {
        int pk = s_feat[nl * 64 + l];
        float f0 = bflo(pk), f1 = bfhi(pk);
        float ss = f0 * av.x + f1 * av.y;
        float sd = f0 * dv.x + f1 * dv.y;
#pragma unroll
        for (int off = 1; off < 64; off <<= 1) {
            ss += __shfl_xor(ss, off);
            sd += __shfl_xor(sd, off);
        }
        if (l == 0) { s_as[nl] = ss; s_ad[nl] = sd; }
    }
    __syncthreads();

    for (int j = tid; j < EPG; j += 512) {
        int pk = s_wc[j].y;
        s_wc[j].x = __float_as_int(leaky(s_as[pk & 255] + s_ad[pk >> 8]));
    }
    __syncthreads();

    if (tid < NPG) {
        float m = leaky(s_as[tid] + s_ad[tid]);
        int r0 = s_row[tid], r1 = s_row[tid + 1];
        for (int j = r0; j < r1; ++j) m = fmaxf(m, __int_as_float(s_wc[j].x));
        s_m[tid] = m;
    }
    __syncthreads();

    for (int j = tid; j < EPG; j += 512) {
        int2 e = s_wc[j];
        s_wc[j].x = __float_as_int(__expf(__int_as_float(e.x) - s_m[e.y >> 8]));
    }
    __syncthreads();

    if (tid < NPG) {
        float rs = __expf(leaky(s_as[tid] + s_ad[tid]) - s_m[tid]);
        int r0 = s_row[tid], r1 = s_row[tid + 1];
        for (int j = r0; j < r1; ++j) rs += __int_as_float(s_wc[j].x);
        s_inv[tid] = 1.0f / (rs + 1e-16f);
    }
    __syncthreads();

    const float2 bv = ((const float2*)b2)[l];
    const float4 wcv = ((const float4*)Wc)[l];
    const float bc0 = bc[0], bc1 = bc[1];
    float accs0 = 0.0f, accs1 = 0.0f;
    for (int nl = w; nl < NPG; nl += 8) {
        const int r0 = s_row[nl], r1 = s_row[nl + 1];
        const float wself = __expf(leaky(s_as[nl] + s_ad[nl]) - s_m[nl]);
        int spk = s_feat[nl * 64 + l];
        float a0 = wself * bflo(spk), a1 = wself * bfhi(spk);
        float c0 = 0.0f, c1 = 0.0f;
        int j = r0;
        for (; j + 4 <= r1; j += 4) {
            int2 e0 = s_wc[j], e1 = s_wc[j + 1], e2 = s_wc[j + 2], e3 = s_wc[j + 3];
            int p0 = s_feat[(e0.y & 255) * 64 + l];
            int p1 = s_feat[(e1.y & 255) * 64 + l];
            int p2 = s_feat[(e2.y & 255) * 64 + l];
            int p3 = s_feat[(e3.y & 255) * 64 + l];
            float w0 = __int_as_float(e0.x), w1 = __int_as_float(e1.x);
            float w2 = __int_as_float(e2.x), w3 = __int_as_float(e3.x);
            a0 += w0 * bflo(p0); a1 += w0 * bfhi(p0);
            c0 += w1 * bflo(p1); c1 += w1 * bfhi(p1);
            a0 += w2 * bflo(p2); a1 += w2 * bfhi(p2);
            c0 += w3 * bflo(p3); c1 += w3 * bfhi(p3);
        }
        for (; j < r1; ++j) {
            int2 e0 = s_wc[j];
            int p0 = s_feat[(e0.y & 255) * 64 + l];
            float w0 = __int_as_float(e0.x);
            a0 += w0 * bflo(p0); a1 += w0 * bfhi(p0);
        }
        const float inv = s_inv[nl];
        float o0 = fmaxf((a0 + c0) * inv + bv.x, 0.0f);
        float o1 = fmaxf((a1 + c1) * inv + bv.y, 0.0f);
        float z0 = o0 * wcv.x + o1 * wcv.z;
        float z1 = o0 * wcv.y + o1 * wcv.w;
#pragma unroll
        for (int off = 1; off < 64; off <<= 1) {
            z0 += __shfl_xor(z0, off);
            z1 += __shfl_xor(z1, off);
        }
        z0 += bc0; z1 += bc1;
        float mm = fmaxf(z0, z1);
        float e0 = __expf(z0 - mm), e1 = __expf(z1 - mm);
        float is = 1.0f / (e0 + e1);
        float s0v = e0 * is, s1v = e1 * is;
        if (l == 0) s_Sv[nl] = make_float2(s0v, s1v);
        accs0 += s0v * o0;
        accs1 += s0v * o1;
    }
    s_red[w * 128 + 2 * l]     = accs0;
    s_red[w * 128 + 2 * l + 1] = accs1;
    __syncthreads();

    // S^T A S over edges (order-independent; use CSR-ordered list)
    float a00 = 0, a01 = 0, a10 = 0, a11 = 0;
    for (int j = tid; j < EPG; j += 512) {
        int pk = s_wc[j].y;
        float2 Ss = s_Sv[pk & 255];
        float2 Sd = s_Sv[pk >> 8];
        a00 += Ss.x * Sd.x; a01 += Ss.x * Sd.y;
        a10 += Ss.y * Sd.x; a11 += Ss.y * Sd.y;
    }
#pragma unroll
    for (int off = 32; off > 0; off >>= 1) {
        a00 += __shfl_down(a00, off); a01 += __shfl_down(a01, off);
        a10 += __shfl_down(a10, off); a11 += __shfl_down(a11, off);
    }
    if (l == 0) { s_aggr[w][0] = a00; s_aggr[w][1] = a01; s_aggr[w][2] = a10; s_aggr[w][3] = a11; }
    __syncthreads();

    if (tid < 128) {
        float s = 0.0f;
#pragma unroll
        for (int w8 = 0; w8 < 8; ++w8) s += s_red[w8 * 128 + tid];
        sub[(size_t)g * HID + tid] = s;
    }
    if (tid < 4) {
        float s = 0.0f;
#pragma unroll
        for (int w8 = 0; w8 < 8; ++w8) s += s_aggr[w8][tid];
        agg[g * 4 + tid] = s;
    }
}

__global__ __launch_bounds__(256)
void loss_kernel(const float* __restrict__ agg, float* __restrict__ out_loss)
{
    int tid = threadIdx.x;   // == graph id, G == 256
    float a00 = agg[tid*4 + 0], a01 = agg[tid*4 + 1];
    float a10 = agg[tid*4 + 2], a11 = agg[tid*4 + 3];
    float rn0 = fmaxf(fabsf(a00) + fabsf(a01), 1e-5f);
    float rn1 = fmaxf(fabsf(a10) + fabsf(a11), 1e-5f);
    float d0 = a00 / rn0 - 1.0f, d1 = a11 / rn1 - 1.0f;
    float contrib = 0.5f * (d0*d0 + d1*d1);
    for (int off = 32; off > 0; off >>= 1) contrib += __shfl_down(contrib, off);
    __shared__ float sred[4];
    if ((tid & 63) == 0) sred[tid >> 6] = contrib;
    __syncthreads();
    if (tid == 0)
        out_loss[0] = (sred[0] + sred[1] + sred[2] + sred[3]) * (1.0f / N_GRAPH);
}

// ---------------- final MLP head ----------------
__global__ __launch_bounds__(128)
void final_kernel(const float* __restrict__ sub, const float* __restrict__ Wf1,
                  const float* __restrict__ bf1, const float* __restrict__ Wf2,
                  const float* __restrict__ bf2, float* __restrict__ out)
{
    __shared__ float s_sub[128];
    __shared__ float s_fc[128];
    const int g = blockIdx.x, t = threadIdx.x;
    s_sub[t] = sub[g*HID + t];
    __syncthreads();
    float acc = bf1[t];
    for (int c = 0; c < 128; ++c)
        acc += s_sub[c] * Wf1[c*128 + t];
    s_fc[t] = fmaxf(acc, 0.0f);
    __syncthreads();
    if (t < 2) {
        float z = bf2[t];
        for (int j = 0; j < 128; ++j) z += s_fc[j] * Wf2[j*2 + t];
        out[g*2 + t] = z;
    }
}

extern "C" void kernel_launch(void* const* d_in, const int* in_sizes, int n_in,
                              void* d_out, int out_size, void* d_ws, size_t ws_size,
                              hipStream_t stream)
{
    const float* x   = (const float*)d_in[0];
    const int*   ei  = (const int*)d_in[1];
    const float* W1  = (const float*)d_in[3];
    const float* as1 = (const float*)d_in[4];
    const float* ad1 = (const float*)d_in[5];
    const float* b1  = (const float*)d_in[6];
    const float* W2  = (const float*)d_in[7];
    const float* as2 = (const float*)d_in[8];
    const float* ad2 = (const float*)d_in[9];
    const float* b2  = (const float*)d_in[10];
    const float* Wc  = (const float*)d_in[11];
    const float* bc  = (const float*)d_in[12];
    const float* Wf1 = (const float*)d_in[13];
    const float* bf1 = (const float*)d_in[14];
    const float* Wf2 = (const float*)d_in[15];
    const float* bf2 = (const float*)d_in[16];
    const int* src0 = ei;
    const int* dst0 = ei + N_EDGE;

    char* ws = (char*)d_ws;
    unsigned short* H1b = (unsigned short*)(ws + OFF_H1B);
    unsigned short* H2b = (unsigned short*)(ws + OFF_H2B);
    short* Wt1   = (short*)(ws + OFF_WT1);
    short* Wt2   = (short*)(ws + OFF_WT2);
    float* aggb  = (float*)(ws + OFF_AGG);
    float* subb  = (float*)(ws + OFF_SUB);
    unsigned short* eord = (unsigned short*)(ws + OFF_EORD);
    int*   rowsb = (int*)(ws + OFF_ROWS);
    float* out   = (float*)d_out;

    transpose_cvt_kernel<<<(F_IN*HC + 255)/256, 256, 0, stream>>>(W1, Wt1, F_IN, HC);
    transpose_cvt_kernel<<<(HC*HID + 255)/256, 256, 0, stream>>>(W2, Wt2, HC, HID);
    csr_kernel<<<N_GRAPH, 256, 0, stream>>>(src0, dst0, eord, rowsb);

    // GEMM1: H1b = bf16(x @ W1), 64x128 tiles
    gemm_xw1_kernel<<<(N_NODES/64) * (HC/128), 256, 0, stream>>>(
        x, Wt1, H1b, N_NODES, HC, F_IN);

    // GAT1, in-place on H1b
    gat1_kernel<<<dim3(N_GRAPH, HEADS), 512, 0, stream>>>(
        H1b, eord, rowsb, as1, ad1, b1, H1b);

    // GEMM2: H2b = bf16(h1 @ W2), 64x128 tiles
    gemm_bf16_kernel<<<(N_NODES/64) * (HID/128), 256, 0, stream>>>(
        (const short*)H1b, Wt2, H2b, N_NODES, HID, HC);

    // GAT2 + cluster softmax + fused sub-pool + S^T A S
    gat2_kernel<<<N_GRAPH, 512, 0, stream>>>(
        H2b, eord, rowsb, as2, ad2, b2, Wc, bc, subb, aggb);

    loss_kernel<<<1, 256, 0, stream>>>(aggb, out + N_GRAPH*2);
    final_kernel<<<N_GRAPH, 128, 0, stream>>>(subb, Wf1, bf1, Wf2, bf2, out);

    (void)in_sizes; (void)n_in; (void)out_size; (void)ws_size;
}

// Round 6
// 505.175 us; speedup vs baseline: 1.0651x; 1.0651x over previous
//
#include <hip/hip_runtime.h>
#include <hip/hip_bf16.h>
#include <cstdint>

#define N_NODES 51200
#define N_GRAPH 256
#define NPG     200
#define N_EDGE  409600
#define EPG     1600
#define F_IN    768
#define HID     128
#define HEADS   4
#define HC      512   // HEADS*HID

typedef __attribute__((ext_vector_type(8))) short short8;
typedef __attribute__((ext_vector_type(4))) float floatx4;

// ---------------- workspace layout (bytes) ----------------
constexpr size_t OFF_H1B    = 0;                                       // bf16 [N,512]
constexpr size_t OFF_H2B    = OFF_H1B + (size_t)N_NODES * HC * 2;      // bf16 [N,128]
constexpr size_t OFF_H2F    = OFF_H2B + (size_t)N_NODES * HID * 2;     // (unused)
constexpr size_t OFF_WT1    = OFF_H2F + (size_t)N_NODES * HID * 4;     // bf16 [512][768]
constexpr size_t OFF_WT2    = OFF_WT1 + (size_t)HC * F_IN * 2;         // bf16 [128][512]
constexpr size_t OFF_S      = OFF_WT2 + (size_t)HID * HC * 2;          // (unused)
constexpr size_t OFF_AGG    = OFF_S + (size_t)N_NODES * 2 * 4;
constexpr size_t OFF_SUB    = OFF_AGG + (size_t)N_GRAPH * 4 * 4;
constexpr size_t OFF_EORD   = OFF_SUB + (size_t)N_GRAPH * HID * 4;     // u16 [G][EPG]
constexpr size_t OFF_ROWS   = OFF_EORD + (size_t)N_GRAPH * EPG * 2;    // i32 [G][NPG+1]

__device__ __forceinline__ float leaky(float x) { return x >= 0.0f ? x : 0.2f * x; }

__device__ __forceinline__ unsigned short f2bf(float f) {
    unsigned int u = __float_as_uint(f);
    u += 0x7fffu + ((u >> 16) & 1u);            // RNE
    return (unsigned short)(u >> 16);
}
__device__ __forceinline__ float bflo(int p) { return __uint_as_float((unsigned)p << 16); }
__device__ __forceinline__ float bfhi(int p) { return __uint_as_float((unsigned)p & 0xffff0000u); }

__device__ __forceinline__ unsigned int cvtpk(float lo, float hi) {
    unsigned int r;
    asm("v_cvt_pk_bf16_f32 %0, %1, %2" : "=v"(r) : "v"(lo), "v"(hi));
    return r;
}

__device__ __forceinline__ void gl_lds16(const void* g, void* l) {
    __builtin_amdgcn_global_load_lds(
        (__attribute__((address_space(1))) void*)(g),
        (__attribute__((address_space(3))) void*)(l),
        16, 0, 0);
}

// ---------------- W [K][N] fp32 -> Wt [N][K] bf16 ----------------
__global__ __launch_bounds__(256)
void transpose_cvt_kernel(const float* __restrict__ W, short* __restrict__ Wt,
                          int K, int Nn)
{
    int idx = blockIdx.x * 256 + threadIdx.x;
    if (idx >= K * Nn) return;
    int k = idx / Nn, n = idx % Nn;
    Wt[(size_t)n * K + k] = (short)f2bf(W[idx]);
}

// ---------------- GEMM1: 256x256 tile, fp32 A staged raw, cvt on LDS read ------------
// v6 (resubmit): TRAFFIC-MINIMAL. Staged bytes = A*2 + B*200 = 471MB (was 922 at 128²).
// 8 waves (2Mx4N, wave tile 128x64, acc 128 VGPR). 3-buffer counted-vmcnt(6).
// n-fast decode + XCD swizzle => both n-halves of an m-tile land on the SAME XCD
// => A's 2nd read + all B re-reads are L2 hits (escape the ~6.3 TB/s L3 ceiling).
__global__ __launch_bounds__(512, 2)
void gemm_xw1_kernel(const float* __restrict__ A, const short* __restrict__ Bt,
                     unsigned short* __restrict__ C, int M, int Nn, int K)
{
    __shared__ __align__(16) float Asm[3][256 * 32];   // 96 KB
    __shared__ __align__(16) short Bsm[3][256 * 32];   // 48 KB  (144 KB total)
    const int tid = threadIdx.x;
    const int w = tid >> 6, l = tid & 63;

    const int nwg = gridDim.x;                          // 400, %8==0
    int wg = blockIdx.x;
    wg = (wg & 7) * (nwg >> 3) + (wg >> 3);             // XCD-chunked, m-contig per XCD
    const int nbx = Nn >> 8;                            // 512/256 = 2
    const int m0 = (wg / nbx) * 256;
    const int n0 = (wg % nbx) * 256;
    const int wr = w >> 2, wc = w & 3;                  // 2x4 wave grid, tile 128x64

    floatx4 acc[8][4];
#pragma unroll
    for (int i = 0; i < 8; ++i)
#pragma unroll
        for (int j = 0; j < 4; ++j) acc[i][j] = (floatx4)0.0f;

    const short* bgp = Bt + (size_t)(n0 + w * 32 + (l & 15)) * K + ((l >> 4) * 8);
    const float* agp = A + (size_t)(m0 + w * 32 + (l & 7)) * K + ((l >> 3) * 4);
    const int nt = K >> 5;      // 24

    // A frag float-offsets (chunk = 8 rows x 32 floats = 1KB, lane-linear)
    int aB[8];
#pragma unroll
    for (int mi = 0; mi < 8; ++mi) {
        const int r = wr * 128 + mi * 16 + (l & 15);
        aB[mi] = (r >> 3) * 256 + (l >> 4) * 64 + (r & 7) * 4;
    }
    const int bB0 = wc * 2048 + l * 8;                 // shorts; chunk = 16 n-rows

#define STAGEX(buf, t) {                                                        \
        const int ko_ = (t) * 32;                                               \
        gl_lds16(agp + ko_,              &Asm[buf][(w * 4 + 0) * 256]);         \
        gl_lds16(agp + 8 * K + ko_,      &Asm[buf][(w * 4 + 1) * 256]);         \
        gl_lds16(agp + 16 * K + ko_,     &Asm[buf][(w * 4 + 2) * 256]);         \
        gl_lds16(agp + 24 * K + ko_,     &Asm[buf][(w * 4 + 3) * 256]);         \
        gl_lds16(bgp + ko_,              &Bsm[buf][w * 1024]);                  \
        gl_lds16(bgp + 16 * K + ko_,     &Bsm[buf][w * 1024 + 512]); }

#define COMPUTEX(buf) {                                                         \
        short8 bfr[4];                                                          \
        _Pragma("unroll")                                                       \
        for (int ni = 0; ni < 4; ++ni)                                          \
            bfr[ni] = *(const short8*)&Bsm[buf][bB0 + ni * 512];                \
        _Pragma("unroll")                                                       \
        for (int mh = 0; mh < 2; ++mh) {                                        \
            short8 af[4];                                                       \
            _Pragma("unroll")                                                   \
            for (int q = 0; q < 4; ++q) {                                       \
                float4 v0 = *(const float4*)&Asm[buf][aB[mh * 4 + q]];          \
                float4 v1 = *(const float4*)&Asm[buf][aB[mh * 4 + q] + 32];     \
                uint4 pk;                                                       \
                pk.x = cvtpk(v0.x, v0.y); pk.y = cvtpk(v0.z, v0.w);             \
                pk.z = cvtpk(v1.x, v1.y); pk.w = cvtpk(v1.z, v1.w);             \
                af[q] = *reinterpret_cast<short8*>(&pk);                        \
            }                                                                   \
            _Pragma("unroll")                                                   \
            for (int q = 0; q < 4; ++q)                                         \
                _Pragma("unroll")                                               \
                for (int ni = 0; ni < 4; ++ni)                                  \
                    acc[mh * 4 + q][ni] = __builtin_amdgcn_mfma_f32_16x16x32_bf16( \
                        af[q], bfr[ni], acc[mh * 4 + q][ni], 0, 0, 0);          \
        } }

    // prologue: tiles 0,1 in flight (12 loads/wave), tile0 must land
    STAGEX(0, 0);
    STAGEX(1, 1);
    asm volatile("s_waitcnt vmcnt(6)" ::: "memory");
    __builtin_amdgcn_s_barrier();

    int cur3 = 0;
    for (int t = 0; t < nt; ++t) {
        int nn3 = cur3 + 2; if (nn3 >= 3) nn3 -= 3;
        if (t + 2 < nt) STAGEX(nn3, t + 2);
        COMPUTEX(cur3);
        if (t + 1 < nt) {
            if (t + 2 < nt) asm volatile("s_waitcnt vmcnt(6) lgkmcnt(0)" ::: "memory");
            else            asm volatile("s_waitcnt vmcnt(0) lgkmcnt(0)" ::: "memory");
            __builtin_amdgcn_s_barrier();
        }
        cur3 += 1; if (cur3 == 3) cur3 = 0;
    }
#undef STAGEX
#undef COMPUTEX

    const int lr = (l >> 4) * 4, lc = l & 15;
#pragma unroll
    for (int mi = 0; mi < 8; ++mi)
#pragma unroll
        for (int ni = 0; ni < 4; ++ni) {
            const size_t base = (size_t)(m0 + wr * 128 + mi * 16 + lr) * Nn
                              + (n0 + wc * 64 + ni * 16 + lc);
#pragma unroll
            for (int rr = 0; rr < 4; ++rr)
                C[base + (size_t)rr * Nn] = f2bf(acc[mi][ni][rr]);
        }
}

// ---------------- GEMM2: bf16 A @ bf16 Bt^T, 128x128, counted-vmcnt 3-buffer ---------
// R2-proven kernel. Nn=128 => nbx=1 => A read exactly once (52MB); B (131KB) L2-resident
// per XCD thanks to m-contiguous swizzle. Total staged ~105MB.
__global__ __launch_bounds__(256)
void gemm_bf16_kernel(const short* __restrict__ Ab, const short* __restrict__ Bt,
                      unsigned short* __restrict__ C, int M, int Nn, int K)
{
    __shared__ __align__(16) short Bblob[3][4096];   // 24 KB
    __shared__ __align__(16) short Ablob[3][4096];   // 24 KB
    const int tid = threadIdx.x;
    const int w = tid >> 6, l = tid & 63;

    const int nwg = gridDim.x;
    int wg = blockIdx.x;
    wg = (wg & 7) * (nwg >> 3) + (wg >> 3);
    const int nbx = Nn >> 7;
    const int m0 = (wg / nbx) * 128;
    const int n0 = (wg % nbx) * 128;
    const int wr = w >> 1, wc = w & 1;
    const int wofs = w * 1024;

    floatx4 acc[4][4];
#pragma unroll
    for (int i = 0; i < 4; ++i)
#pragma unroll
        for (int j = 0; j < 4; ++j) acc[i][j] = (floatx4)0.0f;

    const short* bgp = Bt + (size_t)(n0 + w * 32 + (l & 15)) * K + ((l >> 4) * 8);
    const short* agp = Ab + (size_t)(m0 + w * 32 + (l & 15)) * K + ((l >> 4) * 8);
    const int nt = K >> 5;

    auto compute = [&](int bi) {
        short8 af[4], bfr[4];
#pragma unroll
        for (int mi = 0; mi < 4; ++mi)
            af[mi] = *(const short8*)&Ablob[bi][(wr * 4 + mi) * 512 + l * 8];
#pragma unroll
        for (int ni = 0; ni < 4; ++ni)
            bfr[ni] = *(const short8*)&Bblob[bi][(wc * 4 + ni) * 512 + l * 8];
#pragma unroll
        for (int mi = 0; mi < 4; ++mi)
#pragma unroll
            for (int ni = 0; ni < 4; ++ni)
                acc[mi][ni] = __builtin_amdgcn_mfma_f32_16x16x32_bf16(
                    af[mi], bfr[ni], acc[mi][ni], 0, 0, 0);
    };

    gl_lds16(agp,               &Ablob[0][wofs]);
    gl_lds16(agp + 16 * K,      &Ablob[0][wofs + 512]);
    gl_lds16(bgp,               &Bblob[0][wofs]);
    gl_lds16(bgp + 16 * K,      &Bblob[0][wofs + 512]);
    gl_lds16(agp + 32,          &Ablob[1][wofs]);
    gl_lds16(agp + 16 * K + 32, &Ablob[1][wofs + 512]);
    gl_lds16(bgp + 32,          &Bblob[1][wofs]);
    gl_lds16(bgp + 16 * K + 32, &Bblob[1][wofs + 512]);
    asm volatile("s_waitcnt vmcnt(4)" ::: "memory");
    __builtin_amdgcn_s_barrier();

    int cur3 = 0;
    for (int t = 0; t < nt; ++t) {
        int nn3 = cur3 + 2; if (nn3 >= 3) nn3 -= 3;
        if (t + 2 < nt) {
            const int kk = (t + 2) << 5;
            gl_lds16(agp + kk,          &Ablob[nn3][wofs]);
            gl_lds16(agp + 16 * K + kk, &Ablob[nn3][wofs + 512]);
            gl_lds16(bgp + kk,          &Bblob[nn3][wofs]);
            gl_lds16(bgp + 16 * K + kk, &Bblob[nn3][wofs + 512]);
        }
        compute(cur3);
        if (t + 1 < nt) {
            if (t + 2 < nt) asm volatile("s_waitcnt vmcnt(4) lgkmcnt(0)" ::: "memory");
            else            asm volatile("s_waitcnt vmcnt(0) lgkmcnt(0)" ::: "memory");
            __builtin_amdgcn_s_barrier();
        }
        cur3 += 1; if (cur3 == 3) cur3 = 0;
    }

    const int lr = (l >> 4) * 4, lc = l & 15;
#pragma unroll
    for (int mi = 0; mi < 4; ++mi)
#pragma unroll
        for (int ni = 0; ni < 4; ++ni) {
            const size_t base = (size_t)(m0 + wr * 64 + mi * 16 + lr) * Nn
                              + (n0 + wc * 64 + ni * 16 + lc);
#pragma unroll
            for (int rr = 0; rr < 4; ++rr)
                C[base + (size_t)rr * Nn] = f2bf(acc[mi][ni][rr]);
        }
}

// ---------------- CSR prep: one block per graph, built ONCE for gat1(x4)+gat2 --------
__global__ __launch_bounds__(256)
void csr_kernel(const int* __restrict__ src0, const int* __restrict__ dst0,
                unsigned short* __restrict__ eord, int* __restrict__ rows)
{
    const int g = blockIdx.x, tid = threadIdx.x;
    __shared__ unsigned short s_eraw[EPG];
    __shared__ int s_cnt[NPG];
    __shared__ int s_scan[256];
    __shared__ int s_row[NPG + 1];
    const int gbase = g * NPG;

    if (tid < NPG) s_cnt[tid] = 0;
    for (int j = tid; j < EPG; j += 256) {
        int s = src0[g * EPG + j] - gbase;
        int d = dst0[g * EPG + j] - gbase;
        s_eraw[j] = (unsigned short)(s | (d << 8));
    }
    __syncthreads();
    for (int j = tid; j < EPG; j += 256)
        atomicAdd(&s_cnt[s_eraw[j] >> 8], 1);
    __syncthreads();
    {
        int v = (tid < NPG) ? s_cnt[tid] : 0;
        s_scan[tid] = v;
        __syncthreads();
        for (int off = 1; off < 256; off <<= 1) {
            int u = (tid >= off) ? s_scan[tid - off] : 0;
            __syncthreads();
            s_scan[tid] += u;
            __syncthreads();
        }
        if (tid < NPG) s_row[tid + 1] = s_scan[tid];
        if (tid == 0) s_row[0] = 0;
        __syncthreads();
        if (tid < NPG) s_scan[tid] = s_row[tid];   // cursors
    }
    __syncthreads();
    for (int j = tid; j < EPG; j += 256) {
        int pk = s_eraw[j];
        int p = atomicAdd(&s_scan[pk >> 8], 1);
        eord[(size_t)g * EPG + p] = (unsigned short)pk;
    }
    if (tid <= NPG) rows[g * (NPG + 1) + tid] = s_row[tid];
}

// ---------------- GAT layer 1: prebuilt CSR, 8 waves ----------------
__global__ __launch_bounds__(512)
void gat1_kernel(const unsigned short* __restrict__ H,
                 const unsigned short* __restrict__ eord, const int* __restrict__ rows,
                 const float* __restrict__ a_s, const float* __restrict__ a_d,
                 const float* __restrict__ b1, unsigned short* __restrict__ out)
{
    const int g = blockIdx.x, h = blockIdx.y;
    __shared__ int   s_feat[NPG * 64];            // 51.2 KB
    __shared__ float s_as[NPG], s_ad[NPG], s_m[NPG], s_inv[NPG];
    __shared__ int   s_row[NPG + 1];
    __shared__ int2  s_wc[EPG];                   // 12.8 KB
    const int tid = threadIdx.x, w = tid >> 6, l = tid & 63;
    const int gbase = g * NPG;

    for (int flat = tid; flat < NPG * 16; flat += 512) {
        int row = flat >> 4, q = flat & 15;
        uint4 v = *(const uint4*)(H + (size_t)(gbase + row) * HC + h * HID + q * 8);
        *(uint4*)&s_feat[row * 64 + q * 4] = v;
    }
    for (int j = tid; j < EPG; j += 512)
        s_wc[j].y = eord[(size_t)g * EPG + j];
    if (tid <= NPG) s_row[tid] = rows[g * (NPG + 1) + tid];
    __syncthreads();

    const float2 av = ((const float2*)(a_s + h * HID))[l];
    const float2 dv = ((const float2*)(a_d + h * HID))[l];
    for (int nl = w; nl < NPG; nl += 8) {
        int pk = s_feat[nl * 64 + l];
        float f0 = bflo(pk), f1 = bfhi(pk);
        float ss = f0 * av.x + f1 * av.y;
        float sd = f0 * dv.x + f1 * dv.y;
#pragma unroll
        for (int off = 1; off < 64; off <<= 1) {
            ss += __shfl_xor(ss, off);
            sd += __shfl_xor(sd, off);
        }
        if (l == 0) { s_as[nl] = ss; s_ad[nl] = sd; }
    }
    __syncthreads();

    for (int j = tid; j < EPG; j += 512) {
        int pk = s_wc[j].y;
        s_wc[j].x = __float_as_int(leaky(s_as[pk & 255] + s_ad[pk >> 8]));
    }
    __syncthreads();

    if (tid < NPG) {
        float m = leaky(s_as[tid] + s_ad[tid]);
        int r0 = s_row[tid], r1 = s_row[tid + 1];
        for (int j = r0; j < r1; ++j) m = fmaxf(m, __int_as_float(s_wc[j].x));
        s_m[tid] = m;
    }
    __syncthreads();

    for (int j = tid; j < EPG; j += 512) {
        int2 e = s_wc[j];
        s_wc[j].x = __float_as_int(__expf(__int_as_float(e.x) - s_m[e.y >> 8]));
    }
    __syncthreads();

    if (tid < NPG) {
        float rs = __expf(leaky(s_as[tid] + s_ad[tid]) - s_m[tid]);
        int r0 = s_row[tid], r1 = s_row[tid + 1];
        for (int j = r0; j < r1; ++j) rs += __int_as_float(s_wc[j].x);
        s_inv[tid] = 1.0f / (rs + 1e-16f);
    }
    __syncthreads();

    const float2 bv = ((const float2*)(b1 + h * HID))[l];
    for (int nl = w; nl < NPG; nl += 8) {
        const int r0 = s_row[nl], r1 = s_row[nl + 1];
        const float wself = __expf(leaky(s_as[nl] + s_ad[nl]) - s_m[nl]);
        int spk = s_feat[nl * 64 + l];
        float a0 = wself * bflo(spk), a1 = wself * bfhi(spk);
        float c0 = 0.0f, c1 = 0.0f;
        int j = r0;
        for (; j + 4 <= r1; j += 4) {
            int2 e0 = s_wc[j], e1 = s_wc[j + 1], e2 = s_wc[j + 2], e3 = s_wc[j + 3];
            int p0 = s_feat[(e0.y & 255) * 64 + l];
            int p1 = s_feat[(e1.y & 255) * 64 + l];
            int p2 = s_feat[(e2.y & 255) * 64 + l];
            int p3 = s_feat[(e3.y & 255) * 64 + l];
            float w0 = __int_as_float(e0.x), w1 = __int_as_float(e1.x);
            float w2 = __int_as_float(e2.x), w3 = __int_as_float(e3.x);
            a0 += w0 * bflo(p0); a1 += w0 * bfhi(p0);
            c0 += w1 * bflo(p1); c1 += w1 * bfhi(p1);
            a0 += w2 * bflo(p2); a1 += w2 * bfhi(p2);
            c0 += w3 * bflo(p3); c1 += w3 * bfhi(p3);
        }
        for (; j < r1; ++j) {
            int2 e0 = s_wc[j];
            int p0 = s_feat[(e0.y & 255) * 64 + l];
            float w0 = __int_as_float(e0.x);
            a0 += w0 * bflo(p0); a1 += w0 * bfhi(p0);
        }
        const float inv = s_inv[nl];
        float o0 = (a0 + c0) * inv + bv.x;
        float o1 = (a1 + c1) * inv + bv.y;
        unsigned int st = (unsigned int)f2bf(fmaxf(o0, 0.0f))
                        | ((unsigned int)f2bf(fmaxf(o1, 0.0f)) << 16);
        *(unsigned int*)&out[(size_t)(gbase + nl) * HC + h * HID + 2 * l] = st;
    }
}

// ---------------- GAT layer 2 + cluster softmax + fused sub-pool + S^T A S -----------
__global__ __launch_bounds__(512)
void gat2_kernel(const unsigned short* __restrict__ H,
                 const unsigned short* __restrict__ eord, const int* __restrict__ rows,
                 const float* __restrict__ a_s, const float* __restrict__ a_d,
                 const float* __restrict__ b2, const float* __restrict__ Wc,
                 const float* __restrict__ bc,
                 float* __restrict__ sub, float* __restrict__ agg)
{
    const int g = blockIdx.x;
    __shared__ int   s_feat[NPG * 64];
    __shared__ float s_as[NPG], s_ad[NPG], s_m[NPG], s_inv[NPG];
    __shared__ int   s_row[NPG + 1];
    __shared__ int2  s_wc[EPG];
    __shared__ float2 s_Sv[NPG];
    __shared__ float  s_red[8 * 128];
    __shared__ float  s_aggr[8][4];
    const int tid = threadIdx.x, w = tid >> 6, l = tid & 63;
    const int gbase = g * NPG;

    for (int flat = tid; flat < NPG * 16; flat += 512) {
        int row = flat >> 4, q = flat & 15;
        uint4 v = *(const uint4*)(H + (size_t)(gbase + row) * HID + q * 8);
        *(uint4*)&s_feat[row * 64 + q * 4] = v;
    }
    for (int j = tid; j < EPG; j += 512)
        s_wc[j].y = eord[(size_t)g * EPG + j];
    if (tid <= NPG) s_row[tid] = rows[g * (NPG + 1) + tid];
    __syncthreads();

    const float2 av = ((const float2*)a_s)[l];
    const float2 dv = ((const float2*)a_d)[l];
    for (int nl = w; nl < NPG; nl += 8) {
        int pk = s_feat[nl * 64 + l];
        float f0 = bflo(pk), f1 = bfhi(pk);
        float ss = f0 * av.x + f1 * av.y;
        float sd = f0 * dv.x + f1 * dv.y;
#pragma unroll
        for (int off = 1; off < 64; off <<= 1) {
            ss += __shfl_xor(ss, off);
            sd += __shfl_xor(sd, off);
        }
        if (l == 0) { s_as[nl] = ss; s_ad[nl] = sd; }
    }
    __syncthreads();

    for (int j = tid; j < EPG; j += 512) {
        int pk = s_wc[j].y;
        s_wc[j].x = __float_as_int(leaky(s_as[pk & 255] + s_ad[pk >> 8]));
    }
    __syncthreads();

    if (tid < NPG) {
        float m = leaky(s_as[tid] + s_ad[tid]);
        int r0 = s_row[tid], r1 = s_row[tid + 1];
        for (int j = r0; j < r1; ++j) m = fmaxf(m, __int_as_float(s_wc[j].x));
        s_m[tid] = m;
    }
    __syncthreads();

    for (int j = tid; j < EPG; j += 512) {
        int2 e = s_wc[j];
        s_wc[j].x = __float_as_int(__expf(__int_as_float(e.x) - s_m[e.y >> 8]));
    }
    __syncthreads();

    if (tid < NPG) {
        float rs = __expf(leaky(s_as[tid] + s_ad[tid]) - s_m[tid]);
        int r0 = s_row[tid], r1 = s_row[tid + 1];
        for (int j = r0; j < r1; ++j) rs += __int_as_float(s_wc[j].x);
        s_inv[tid] = 1.0f / (rs + 1e-16f);
    }
    __syncthreads();

    const float2 bv = ((const float2*)b2)[l];
    const float4 wcv = ((const float4*)Wc)[l];
    const float bc0 = bc[0], bc1 = bc[1];
    float accs0 = 0.0f, accs1 = 0.0f;
    for (int nl = w; nl < NPG; nl += 8) {
        const int r0 = s_row[nl], r1 = s_row[nl + 1];
        const float wself = __expf(leaky(s_as[nl] + s_ad[nl]) - s_m[nl]);
        int spk = s_feat[nl * 64 + l];
        float a0 = wself * bflo(spk), a1 = wself * bfhi(spk);
        float c0 = 0.0f, c1 = 0.0f;
        int j = r0;
        for (; j + 4 <= r1; j += 4) {
            int2 e0 = s_wc[j], e1 = s_wc[j + 1], e2 = s_wc[j + 2], e3 = s_wc[j + 3];
            int p0 = s_feat[(e0.y & 255) * 64 + l];
            int p1 = s_feat[(e1.y & 255) * 64 + l];
            int p2 = s_feat[(e2.y & 255) * 64 + l];
            int p3 = s_feat[(e3.y & 255) * 64 + l];
            float w0 = __int_as_float(e0.x), w1 = __int_as_float(e1.x);
            float w2 = __int_as_float(e2.x), w3 = __int_as_float(e3.x);
            a0 += w0 * bflo(p0); a1 += w0 * bfhi(p0);
            c0 += w1 * bflo(p1); c1 += w1 * bfhi(p1);
            a0 += w2 * bflo(p2); a1 += w2 * bfhi(p2);
            c0 += w3 * bflo(p3); c1 += w3 * bfhi(p3);
        }
        for (; j < r1; ++j) {
            int2 e0 = s_wc[j];
            int p0 = s_feat[(e0.y & 255) * 64 + l];
            float w0 = __int_as_float(e0.x);
            a0 += w0 * bflo(p0); a1 += w0 * bfhi(p0);
        }
        const float inv = s_inv[nl];
        float o0 = fmaxf((a0 + c0) * inv + bv.x, 0.0f);
        float o1 = fmaxf((a1 + c1) * inv + bv.y, 0.0f);
        float z0 = o0 * wcv.x + o1 * wcv.z;
        float z1 = o0 * wcv.y + o1 * wcv.w;
#pragma unroll
        for (int off = 1; off < 64; off <<= 1) {
            z0 += __shfl_xor(z0, off);
            z1 += __shfl_xor(z1, off);
        }
        z0 += bc0; z1 += bc1;
        float mm = fmaxf(z0, z1);
        float e0 = __expf(z0 - mm), e1 = __expf(z1 - mm);
        float is = 1.0f / (e0 + e1);
        float s0v = e0 * is, s1v = e1 * is;
        if (l == 0) s_Sv[nl] = make_float2(s0v, s1v);
        accs0 += s0v * o0;
        accs1 += s0v * o1;
    }
    s_red[w * 128 + 2 * l]     = accs0;
    s_red[w * 128 + 2 * l + 1] = accs1;
    __syncthreads();

    float a00 = 0, a01 = 0, a10 = 0, a11 = 0;
    for (int j = tid; j < EPG; j += 512) {
        int pk = s_wc[j].y;
        float2 Ss = s_Sv[pk & 255];
        float2 Sd = s_Sv[pk >> 8];
        a00 += Ss.x * Sd.x; a01 += Ss.x * Sd.y;
        a10 += Ss.y * Sd.x; a11 += Ss.y * Sd.y;
    }
#pragma unroll
    for (int off = 32; off > 0; off >>= 1) {
        a00 += __shfl_down(a00, off); a01 += __shfl_down(a01, off);
        a10 += __shfl_down(a10, off); a11 += __shfl_down(a11, off);
    }
    if (l == 0) { s_aggr[w][0] = a00; s_aggr[w][1] = a01; s_aggr[w][2] = a10; s_aggr[w][3] = a11; }
    __syncthreads();

    if (tid < 128) {
        float s = 0.0f;
#pragma unroll
        for (int w8 = 0; w8 < 8; ++w8) s += s_red[w8 * 128 + tid];
        sub[(size_t)g * HID + tid] = s;
    }
    if (tid < 4) {
        float s = 0.0f;
#pragma unroll
        for (int w8 = 0; w8 < 8; ++w8) s += s_aggr[w8][tid];
        agg[g * 4 + tid] = s;
    }
}

__global__ __launch_bounds__(256)
void loss_kernel(const float* __restrict__ agg, float* __restrict__ out_loss)
{
    int tid = threadIdx.x;   // == graph id, G == 256
    float a00 = agg[tid*4 + 0], a01 = agg[tid*4 + 1];
    float a10 = agg[tid*4 + 2], a11 = agg[tid*4 + 3];
    float rn0 = fmaxf(fabsf(a00) + fabsf(a01), 1e-5f);
    float rn1 = fmaxf(fabsf(a10) + fabsf(a11), 1e-5f);
    float d0 = a00 / rn0 - 1.0f, d1 = a11 / rn1 - 1.0f;
    float contrib = 0.5f * (d0*d0 + d1*d1);
    for (int off = 32; off > 0; off >>= 1) contrib += __shfl_down(contrib, off);
    __shared__ float sred[4];
    if ((tid & 63) == 0) sred[tid >> 6] = contrib;
    __syncthreads();
    if (tid == 0)
        out_loss[0] = (sred[0] + sred[1] + sred[2] + sred[3]) * (1.0f / N_GRAPH);
}

// ---------------- final MLP head ----------------
__global__ __launch_bounds__(128)
void final_kernel(const float* __restrict__ sub, const float* __restrict__ Wf1,
                  const float* __restrict__ bf1, const float* __restrict__ Wf2,
                  const float* __restrict__ bf2, float* __restrict__ out)
{
    __shared__ float s_sub[128];
    __shared__ float s_fc[128];
    const int g = blockIdx.x, t = threadIdx.x;
    s_sub[t] = sub[g*HID + t];
    __syncthreads();
    float acc = bf1[t];
    for (int c = 0; c < 128; ++c)
        acc += s_sub[c] * Wf1[c*128 + t];
    s_fc[t] = fmaxf(acc, 0.0f);
    __syncthreads();
    if (t < 2) {
        float z = bf2[t];
        for (int j = 0; j < 128; ++j) z += s_fc[j] * Wf2[j*2 + t];
        out[g*2 + t] = z;
    }
}

extern "C" void kernel_launch(void* const* d_in, const int* in_sizes, int n_in,
                              void* d_out, int out_size, void* d_ws, size_t ws_size,
                              hipStream_t stream)
{
    const float* x   = (const float*)d_in[0];
    const int*   ei  = (const int*)d_in[1];
    const float* W1  = (const float*)d_in[3];
    const float* as1 = (const float*)d_in[4];
    const float* ad1 = (const float*)d_in[5];
    const float* b1  = (const float*)d_in[6];
    const float* W2  = (const float*)d_in[7];
    const float* as2 = (const float*)d_in[8];
    const float* ad2 = (const float*)d_in[9];
    const float* b2  = (const float*)d_in[10];
    const float* Wc  = (const float*)d_in[11];
    const float* bc  = (const float*)d_in[12];
    const float* Wf1 = (const float*)d_in[13];
    const float* bf1 = (const float*)d_in[14];
    const float* Wf2 = (const float*)d_in[15];
    const float* bf2 = (const float*)d_in[16];
    const int* src0 = ei;
    const int* dst0 = ei + N_EDGE;

    char* ws = (char*)d_ws;
    unsigned short* H1b = (unsigned short*)(ws + OFF_H1B);
    unsigned short* H2b = (unsigned short*)(ws + OFF_H2B);
    short* Wt1   = (short*)(ws + OFF_WT1);
    short* Wt2   = (short*)(ws + OFF_WT2);
    float* aggb  = (float*)(ws + OFF_AGG);
    float* subb  = (float*)(ws + OFF_SUB);
    unsigned short* eord = (unsigned short*)(ws + OFF_EORD);
    int*   rowsb = (int*)(ws + OFF_ROWS);
    float* out   = (float*)d_out;

    transpose_cvt_kernel<<<(F_IN*HC + 255)/256, 256, 0, stream>>>(W1, Wt1, F_IN, HC);
    transpose_cvt_kernel<<<(HC*HID + 255)/256, 256, 0, stream>>>(W2, Wt2, HC, HID);
    csr_kernel<<<N_GRAPH, 256, 0, stream>>>(src0, dst0, eord, rowsb);

    // GEMM1: H1b = bf16(x @ W1), 256x256 tiles (traffic-minimal), 512 threads
    gemm_xw1_kernel<<<(N_NODES/256) * (HC/256), 512, 0, stream>>>(
        x, Wt1, H1b, N_NODES, HC, F_IN);

    // GAT1, in-place on H1b
    gat1_kernel<<<dim3(N_GRAPH, HEADS), 512, 0, stream>>>(
        H1b, eord, rowsb, as1, ad1, b1, H1b);

    // GEMM2: H2b = bf16(h1 @ W2), 128x128 tiles (A read once)
    gemm_bf16_kernel<<<(N_NODES/128) * (HID/128), 256, 0, stream>>>(
        (const short*)H1b, Wt2, H2b, N_NODES, HID, HC);

    // GAT2 + cluster softmax + fused sub-pool + S^T A S
    gat2_kernel<<<N_GRAPH, 512, 0, stream>>>(
        H2b, eord, rowsb, as2, ad2, b2, Wc, bc, subb, aggb);

    loss_kernel<<<1, 256, 0, stream>>>(aggb, out + N_GRAPH*2);
    final_kernel<<<N_GRAPH, 128, 0, stream>>>(subb, Wf1, bf1, Wf2, bf2, out);

    (void)in_sizes; (void)n_in; (void)out_size; (void)ws_size;
}